// Round 1
// baseline (549.718 us; speedup 1.0000x reference)
//
#include <hip/hip_runtime.h>
#include <math.h>

constexpr int N_SEQ  = 4096;
constexpr int BSZ    = 4;
constexpr int CIN    = 384;
constexpr int CDSSP  = 64;
constexpr int CHID   = 128;
constexpr int NBLK   = 4;
constexpr int NTOK   = BSZ * N_SEQ;        // 16384 tokens
constexpr int TPB    = 32;                 // tokens per MLP block
constexpr int MLP_BLOCKS  = NTOK / TPB;    // 512
constexpr int ZERO_BLOCKS = 2048;
constexpr size_t OUT_ELEMS = (size_t)BSZ * N_SEQ * N_SEQ;  // 67108864

__device__ __forceinline__ float softplus_f(float x) {
    // stable: max(x,0) + log1p(exp(-|x|))  == jnp.logaddexp(x, 0)
    return fmaxf(x, 0.f) + log1pf(expf(-fabsf(x)));
}

// Fused kernel: blocks [0, MLP_BLOCKS) run the MLP (VALU-bound);
// blocks [MLP_BLOCKS, MLP_BLOCKS+ZERO_BLOCKS) zero-fill d_out (HBM-write-bound).
// The two populations co-execute on disjoint pipes.
__global__ __launch_bounds__(256) void mlp_zero_kernel(
    const float* __restrict__ s, const float* __restrict__ s_init,
    const float* __restrict__ dssp,
    const float* __restrict__ W_in,   const float* __restrict__ b_in,
    const float* __restrict__ W_init, const float* __restrict__ b_init,
    const float* __restrict__ W_dssp, const float* __restrict__ b_dssp,
    const float* __restrict__ W1,     const float* __restrict__ b1,
    const float* __restrict__ W2,     const float* __restrict__ b2,
    const float* __restrict__ W_out,  const float* __restrict__ b_out,
    const float* __restrict__ W_mult, const float* __restrict__ b_mult,
    float* __restrict__ ws, float* __restrict__ out)
{
    // LDS: act tile A[k up to 128][36 pad] (t-inner, float4-aligned reads),
    //      weight tile Wl[j=128][65 pad] (k-inner; pad-65 -> bank stride 1,
    //      conflict-free strided reads AND contiguous conflict-free writes).
    __shared__ __align__(16) float A [CHID * 36];   // 18.4 KB
    __shared__ __align__(16) float Wl[CHID * 65];   // 33.3 KB  (total 51.7 KB -> 3 blk/CU)

    if (blockIdx.x >= MLP_BLOCKS) {
        const int zb = (int)blockIdx.x - MLP_BLOCKS;
        const size_t chunk = OUT_ELEMS / ZERO_BLOCKS;          // 32768 floats
        float4* dst = (float4*)(out + (size_t)zb * chunk);
        const int n4 = (int)(chunk / 4);                       // 8192
        const float4 z = make_float4(0.f, 0.f, 0.f, 0.f);
        for (int i = threadIdx.x; i < n4; i += 256) dst[i] = z;
        return;
    }

    const int tid = threadIdx.x;
    const int cg  = tid & 31;   // channel group: owns channels {cg, cg+32, cg+64, cg+96}
    const int tg  = tid >> 5;   // token group:   owns tokens   {4tg .. 4tg+3}
    const int t0  = (int)blockIdx.x * TPB;

    // h accumulators: acc[m][i] = h[token 4tg+i][channel cg+32m]
    float acc[4][4];
    #pragma unroll
    for (int m = 0; m < 4; ++m) {
        const int j = cg + 32 * m;
        const float b = b_in[j] + b_init[j] + b_dssp[j];
        #pragma unroll
        for (int i = 0; i < 4; ++i) acc[m][i] = b;
    }

    // ---- staging helpers ----
    auto stage_act_global = [&](const float* __restrict__ src, int C, int k0) {
        // stage relu(src[t0+t][k0+k]) -> A[k*36+t], k in [0,64), t in [0,32)
        for (int idx = tid; idx < 64 * TPB; idx += 256) {
            const int t = idx >> 6;
            const int k = idx & 63;
            const float v = src[(size_t)(t0 + t) * C + k0 + k];
            A[k * 36 + t] = fmaxf(v, 0.f);
        }
    };
    auto stage_w = [&](const float* __restrict__ W, int K, int k0) {
        // W row-major [128][K]; tile cols k0..k0+63 -> Wl[j*65 + k]
        for (int q = tid; q < CHID * 16; q += 256) {
            const int j  = q >> 4;
            const int kq = q & 15;
            const float4 w4 = *(const float4*)&W[(size_t)j * K + k0 + 4 * kq];
            float* d = &Wl[j * 65 + 4 * kq];
            d[0] = w4.x; d[1] = w4.y; d[2] = w4.z; d[3] = w4.w;
        }
    };
    auto gemm_tile = [&](float (&ac)[4][4], int ak0) {
        #pragma unroll 2
        for (int k = 0; k < 64; ++k) {
            const float4 a = *(const float4*)&A[(ak0 + k) * 36 + 4 * tg];
            const float w0 = Wl[(cg     ) * 65 + k];
            const float w1 = Wl[(cg + 32) * 65 + k];
            const float w2 = Wl[(cg + 64) * 65 + k];
            const float w3 = Wl[(cg + 96) * 65 + k];
            ac[0][0] = fmaf(w0, a.x, ac[0][0]);
            ac[0][1] = fmaf(w0, a.y, ac[0][1]);
            ac[0][2] = fmaf(w0, a.z, ac[0][2]);
            ac[0][3] = fmaf(w0, a.w, ac[0][3]);
            ac[1][0] = fmaf(w1, a.x, ac[1][0]);
            ac[1][1] = fmaf(w1, a.y, ac[1][1]);
            ac[1][2] = fmaf(w1, a.z, ac[1][2]);
            ac[1][3] = fmaf(w1, a.w, ac[1][3]);
            ac[2][0] = fmaf(w2, a.x, ac[2][0]);
            ac[2][1] = fmaf(w2, a.y, ac[2][1]);
            ac[2][2] = fmaf(w2, a.z, ac[2][2]);
            ac[2][3] = fmaf(w2, a.w, ac[2][3]);
            ac[3][0] = fmaf(w3, a.x, ac[3][0]);
            ac[3][1] = fmaf(w3, a.y, ac[3][1]);
            ac[3][2] = fmaf(w3, a.z, ac[3][2]);
            ac[3][3] = fmaf(w3, a.w, ac[3][3]);
        }
    };
    auto dump_relu = [&](float (&ac)[4][4]) {
        // write relu(ac) -> A[j*36 + t] (activations for next matmul)
        #pragma unroll
        for (int m = 0; m < 4; ++m) {
            float4 v;
            v.x = fmaxf(ac[m][0], 0.f);
            v.y = fmaxf(ac[m][1], 0.f);
            v.z = fmaxf(ac[m][2], 0.f);
            v.w = fmaxf(ac[m][3], 0.f);
            *(float4*)&A[(cg + 32 * m) * 36 + 4 * tg] = v;
        }
    };

    // ---- input layer: h = relu(s)Win^T + relu(s_init)Winit^T + relu(dssp)Wd^T (+biases) ----
    {
        const float* srcs[3] = { s, s_init, dssp };
        const float* Wmats[3] = { W_in, W_init, W_dssp };
        const int Ks[3] = { CIN, CIN, CDSSP };
        for (int si = 0; si < 3; ++si) {
            for (int k0 = 0; k0 < Ks[si]; k0 += 64) {
                __syncthreads();                       // protect prev tile reads
                stage_act_global(srcs[si], Ks[si], k0);
                stage_w(Wmats[si], Ks[si], k0);
                __syncthreads();
                gemm_tile(acc, 0);
            }
        }
    }

    // ---- resnet blocks: h += W2 relu(W1 relu(h) + b1) + b2 ----
    for (int rb = 0; rb < NBLK; ++rb) {
        __syncthreads();
        dump_relu(acc);                                // A = relu(h), all 128 rows

        float vacc[4][4];
        #pragma unroll
        for (int m = 0; m < 4; ++m) {
            const float b = b1[rb * CHID + cg + 32 * m];
            #pragma unroll
            for (int i = 0; i < 4; ++i) vacc[m][i] = b;
        }
        for (int k0 = 0; k0 < CHID; k0 += 64) {
            __syncthreads();
            stage_w(W1 + (size_t)rb * CHID * CHID, CHID, k0);
            __syncthreads();
            gemm_tile(vacc, k0);
        }

        __syncthreads();                               // all reads of A done
        dump_relu(vacc);                               // A = relu(v)

        #pragma unroll
        for (int m = 0; m < 4; ++m) {
            const float b = b2[rb * CHID + cg + 32 * m];
            #pragma unroll
            for (int i = 0; i < 4; ++i) acc[m][i] += b;
        }
        for (int k0 = 0; k0 < CHID; k0 += 64) {
            __syncthreads();
            stage_w(W2 + (size_t)rb * CHID * CHID, CHID, k0);
            __syncthreads();
            gemm_tile(acc, k0);
        }
    }

    // ---- output head: 7 dots per token from relu(h) ----
    __syncthreads();
    dump_relu(acc);                                    // A = relu(h) final
    __syncthreads();                                   // Wl free after this point
    {
        const int t = tid >> 3;        // token 0..31
        const int o = tid & 7;         // output 0..6 (7 idle)
        if (o < 7) {
            const float* wr = (o < 5) ? (W_out + (size_t)o * CHID)
                                      : (W_mult + (size_t)(o - 5) * CHID);
            float dotv = (o < 5) ? b_out[o] : b_mult[o - 5];
            #pragma unroll 8
            for (int k = 0; k < CHID; ++k)
                dotv = fmaf(A[k * 36 + t], wr[k], dotv);
            Wl[t * 8 + o] = dotv;      // stash raw head outputs
        }
    }
    __syncthreads();
    if (tid < TPB) {
        const float c0 = Wl[tid * 8 + 0];
        const float c1 = Wl[tid * 8 + 1];
        const float c2 = Wl[tid * 8 + 2];
        const float c3 = Wl[tid * 8 + 3];
        const float c4 = Wl[tid * 8 + 4];
        const float av = Wl[tid * 8 + 5];
        const float bm = Wl[tid * 8 + 6];
        const int g = t0 + tid;
        ws[g]            = softplus_f(c0) * softplus_f(av) + softplus_f(bm); // diag value (unscaled)
        ws[NTOK     + g] = c1;
        ws[2 * NTOK + g] = c2;
        ws[3 * NTOK + g] = c3;
        ws[4 * NTOK + g] = c4;
    }
}

// Writes the three diagonals on top of the zeroed output.
__global__ __launch_bounds__(256) void band_kernel(
    const float* __restrict__ ws, const float* __restrict__ p_sm,
    float* __restrict__ out)
{
    const int g = (int)blockIdx.x * 256 + (int)threadIdx.x;   // 0..16383
    const int b = g >> 12;
    const int i = g & (N_SEQ - 1);
    const float sm = *p_sm;
    const float* v0 = ws;
    const float* c1 = ws + NTOK;
    const float* c2 = ws + 2 * NTOK;
    const float* c3 = ws + 3 * NTOK;
    const float* c4 = ws + 4 * NTOK;
    const size_t rowbase = (size_t)b * N_SEQ * N_SEQ + (size_t)i * N_SEQ;
    out[rowbase + i] = sm * v0[g];
    if (i >= 1) out[rowbase + i - 1] = sm * (c1[g] + c3[g - 1]);
    if (i >= 2) out[rowbase + i - 2] = sm * (c2[g] + c4[g - 2]);
}

extern "C" void kernel_launch(void* const* d_in, const int* in_sizes, int n_in,
                              void* d_out, int out_size, void* d_ws, size_t ws_size,
                              hipStream_t stream)
{
    const float* s      = (const float*)d_in[0];
    const float* s_init = (const float*)d_in[1];
    const float* dssp   = (const float*)d_in[2];
    const float* W_in   = (const float*)d_in[3];
    const float* b_in   = (const float*)d_in[4];
    const float* W_init = (const float*)d_in[5];
    const float* b_initp= (const float*)d_in[6];
    const float* W_dssp = (const float*)d_in[7];
    const float* b_dsspp= (const float*)d_in[8];
    const float* W1     = (const float*)d_in[9];
    const float* b1     = (const float*)d_in[10];
    const float* W2     = (const float*)d_in[11];
    const float* b2     = (const float*)d_in[12];
    const float* W_out  = (const float*)d_in[13];
    const float* b_out  = (const float*)d_in[14];
    const float* W_mult = (const float*)d_in[15];
    const float* b_mult = (const float*)d_in[16];
    const float* sm     = (const float*)d_in[17];
    float* ws  = (float*)d_ws;
    float* out = (float*)d_out;

    mlp_zero_kernel<<<MLP_BLOCKS + ZERO_BLOCKS, 256, 0, stream>>>(
        s, s_init, dssp, W_in, b_in, W_init, b_initp, W_dssp, b_dsspp,
        W1, b1, W2, b2, W_out, b_out, W_mult, b_mult, ws, out);

    band_kernel<<<NTOK / 256, 256, 0, stream>>>(ws, sm, out);
}